// Round 1
// baseline (2304.391 us; speedup 1.0000x reference)
//
#include <hip/hip_runtime.h>
#include <math.h>

#define DIM 128
#define NRES 262144
#define PB 32        // parents per block
#define KT 16        // k-tile width staged in LDS
#define WSTRIDE 644  // padded LDS stride for W tile (rows of 640, +4 pad)
#define XSTRIDE 260  // padded LDS stride for X rows (256 + 4 pad)

__device__ __forceinline__ float sigmoidf_(float x) {
    return 1.0f / (1.0f + __expf(-x));
}

// One tree-LSTM level. h_in/c_in have 2*n_par rows of DIM; outputs n_par rows.
// Parent p's children are rows 2p, 2p+1 (tree structure is transparent in the
// flattened layout since trees are contiguous and power-of-2 sized).
template<bool FIRST>
__global__ __launch_bounds__(256)
void tree_level_kernel(const float* __restrict__ h_in, const float* __restrict__ c_in,
                       const float* __restrict__ W, const float* __restrict__ b,
                       float* __restrict__ h_out, float* __restrict__ c_out,
                       int n_par) {
    __shared__ float Xs[PB * XSTRIDE];  // combined [hl|hr] per parent = contiguous 2 child rows
    __shared__ float Ws[KT * WSTRIDE];  // W tile, transposed: Ws[kk][row]

    const int t = threadIdx.x;
    const int p0 = blockIdx.x * PB;

    // ---- stage X: children rows [2*p0, 2*p0+2*PB) x DIM = PB*256 floats contiguous
    {
        const float4* src = (const float4*)(h_in + (size_t)2 * p0 * DIM);
        const int limit4 = (n_par * 2 - 2 * p0) * DIM / 4;  // remaining float4s in h_in
        #pragma unroll
        for (int j = 0; j < (PB * 256 / 4) / 256; ++j) {    // 8 iters
            int s = j * 256 + t;
            float4 v = (s < limit4) ? src[s] : make_float4(0.f, 0.f, 0.f, 0.f);
            int p = (s * 4) >> 8;
            int k = (s * 4) & 255;
            *(float4*)&Xs[p * XSTRIDE + k] = v;
        }
    }

    const int dgrp = t & 31;   // 32 dim-groups x 4 dims
    const int pgrp = t >> 5;   // 8 parent-groups x 4 parents
    const int d = dgrp * 4;

    float acc[5][4][4];  // [gate][dim][parent]
    #pragma unroll
    for (int g = 0; g < 5; ++g)
        #pragma unroll
        for (int i = 0; i < 4; ++i)
            #pragma unroll
            for (int pp = 0; pp < 4; ++pp) acc[g][i][pp] = 0.f;

    for (int kt = 0; kt < 256 / KT; ++kt) {
        __syncthreads();  // protect Ws from previous iteration (and Xs on first)
        // ---- stage W tile: 640 rows x KT cols, stored transposed Ws[kk][row]
        #pragma unroll
        for (int j = 0; j < (640 * KT / 4) / 256; ++j) {  // 10 iters
            int s = j * 256 + t;
            int r = s >> 2;       // row 0..639
            int q = s & 3;        // float4 index within the KT=16 columns
            float4 w4 = *(const float4*)&W[(size_t)r * 256 + kt * KT + q * 4];
            Ws[(q * 4 + 0) * WSTRIDE + r] = w4.x;
            Ws[(q * 4 + 1) * WSTRIDE + r] = w4.y;
            Ws[(q * 4 + 2) * WSTRIDE + r] = w4.z;
            Ws[(q * 4 + 3) * WSTRIDE + r] = w4.w;
        }
        __syncthreads();
        #pragma unroll
        for (int kk = 0; kk < KT; ++kk) {
            const int k = kt * KT + kk;
            float x[4];
            #pragma unroll
            for (int pp = 0; pp < 4; ++pp)
                x[pp] = Xs[(pgrp * 4 + pp) * XSTRIDE + k];
            #pragma unroll
            for (int g = 0; g < 5; ++g) {
                float4 w = *(const float4*)&Ws[kk * WSTRIDE + g * 128 + d];
                #pragma unroll
                for (int pp = 0; pp < 4; ++pp) {
                    acc[g][0][pp] = fmaf(w.x, x[pp], acc[g][0][pp]);
                    acc[g][1][pp] = fmaf(w.y, x[pp], acc[g][1][pp]);
                    acc[g][2][pp] = fmaf(w.z, x[pp], acc[g][2][pp]);
                    acc[g][3][pp] = fmaf(w.w, x[pp], acc[g][3][pp]);
                }
            }
        }
    }

    // ---- epilogue: bias + gates + cell update
    float4 b_i  = *(const float4*)&b[0 * 128 + d];
    float4 b_fl = *(const float4*)&b[1 * 128 + d];
    float4 b_fr = *(const float4*)&b[2 * 128 + d];
    float4 b_o  = *(const float4*)&b[3 * 128 + d];
    float4 b_g  = *(const float4*)&b[4 * 128 + d];
    const float bi[4]  = {b_i.x,  b_i.y,  b_i.z,  b_i.w};
    const float bfl[4] = {b_fl.x, b_fl.y, b_fl.z, b_fl.w};
    const float bfr[4] = {b_fr.x, b_fr.y, b_fr.z, b_fr.w};
    const float bo[4]  = {b_o.x,  b_o.y,  b_o.z,  b_o.w};
    const float bg[4]  = {b_g.x,  b_g.y,  b_g.z,  b_g.w};

    #pragma unroll
    for (int pp = 0; pp < 4; ++pp) {
        const int P = p0 + pgrp * 4 + pp;
        if (P < n_par) {
            float cl[4] = {0.f, 0.f, 0.f, 0.f}, cr[4] = {0.f, 0.f, 0.f, 0.f};
            if (!FIRST) {
                float4 cl4 = *(const float4*)&c_in[(size_t)(2 * P) * DIM + d];
                float4 cr4 = *(const float4*)&c_in[(size_t)(2 * P + 1) * DIM + d];
                cl[0] = cl4.x; cl[1] = cl4.y; cl[2] = cl4.z; cl[3] = cl4.w;
                cr[0] = cr4.x; cr[1] = cr4.y; cr[2] = cr4.z; cr[3] = cr4.w;
            }
            float4 h4, c4;
            float ho[4], co[4];
            #pragma unroll
            for (int i = 0; i < 4; ++i) {
                float iv = sigmoidf_(acc[0][i][pp] + bi[i]);
                float fl = sigmoidf_(acc[1][i][pp] + bfl[i]);
                float fr = sigmoidf_(acc[2][i][pp] + bfr[i]);
                float ov = sigmoidf_(acc[3][i][pp] + bo[i]);
                float gv = tanhf(acc[4][i][pp] + bg[i]);
                float cn = fl * cl[i] + fr * cr[i] + iv * gv;
                co[i] = cn;
                ho[i] = ov * tanhf(cn);
            }
            h4.x = ho[0]; h4.y = ho[1]; h4.z = ho[2]; h4.w = ho[3];
            c4.x = co[0]; c4.y = co[1]; c4.z = co[2]; c4.w = co[3];
            *(float4*)&h_out[(size_t)P * DIM + d] = h4;
            *(float4*)&c_out[(size_t)P * DIM + d] = c4;
        }
    }
}

// out[0:128] = mean over 4 trees of final h; out[128:256] = 0
__global__ void root_kernel(const float* __restrict__ h_final, float* __restrict__ out) {
    int t = threadIdx.x;  // 256 threads
    if (t < 128) {
        out[t] = 0.25f * (h_final[t] + h_final[128 + t] + h_final[256 + t] + h_final[384 + t]);
    } else if (t < 256) {
        out[t] = 0.0f;
    }
}

// leaves output: row r -> [leaf_emb[r] (128) | zeros (128)]
__global__ void copy_leaves_kernel(const float* __restrict__ leaf, float* __restrict__ out) {
    const float4* lf4 = (const float4*)leaf;
    float4* of4 = (float4*)(out + 256);
    const size_t total = (size_t)NRES * 64;  // 64 float4 per output row
    for (size_t v = (size_t)blockIdx.x * blockDim.x + threadIdx.x; v < total;
         v += (size_t)gridDim.x * blockDim.x) {
        size_t r = v >> 6;
        int c = (int)(v & 63);
        float4 val = (c < 32) ? lf4[(r << 5) + c] : make_float4(0.f, 0.f, 0.f, 0.f);
        of4[v] = val;
    }
}

extern "C" void kernel_launch(void* const* d_in, const int* in_sizes, int n_in,
                              void* d_out, int out_size, void* d_ws, size_t ws_size,
                              hipStream_t stream) {
    const float* leaf = (const float*)d_in[0];
    const float* W_up = (const float*)d_in[1];
    const float* b_up = (const float*)d_in[2];
    float* out = (float*)d_out;

    // Scratch ping-pong buffers carved out of d_out (fully overwritten at the end).
    // A sized for level-1 output (131072 rows x 128), B for level-2 (65536 x 128).
    float* hA = out;
    float* cA = out + 16777216;
    float* hB = out + 33554432;
    float* cB = out + 50331648;

    int n_par = NRES / 2;  // 131072
    tree_level_kernel<true><<<(n_par + PB - 1) / PB, 256, 0, stream>>>(
        leaf, nullptr, W_up, b_up, hA, cA, n_par);

    const float* hin = hA; const float* cin = cA;
    float* ho = hB; float* co = cB;
    for (int lvl = 2; lvl <= 16; ++lvl) {
        n_par >>= 1;
        tree_level_kernel<false><<<(n_par + PB - 1) / PB, 256, 0, stream>>>(
            hin, cin, W_up, b_up, ho, co, n_par);
        const float* th = hin; const float* tc = cin;
        hin = ho; cin = co;
        ho = (float*)th; co = (float*)tc;
    }
    // hin now points at the 4x128 final roots (in the B half; root output doesn't overlap it)
    root_kernel<<<1, 256, 0, stream>>>(hin, out);
    copy_leaves_kernel<<<2048, 256, 0, stream>>>(leaf, out);
}

// Round 2
// 723.301 us; speedup vs baseline: 3.1859x; 3.1859x over previous
//
#include <hip/hip_runtime.h>
#include <math.h>

#define DIM 128
#define NRES 262144

typedef __attribute__((ext_vector_type(8))) short short8;
typedef __attribute__((ext_vector_type(4))) float f32x4;

__device__ __forceinline__ float sigmoidf_(float x) {
    return 1.0f / (1.0f + __expf(-x));
}
__device__ __forceinline__ float tanhf_(float x) {
    // tanh(x) = 1 - 2/(e^2x + 1); graceful at +inf, fine for |x| <= ~20 here
    return 1.0f - 2.0f / (__expf(2.0f * x) + 1.0f);
}
__device__ __forceinline__ unsigned short f2bf(float f) {
    unsigned int u = __float_as_uint(f);
    unsigned int r = u + 0x7FFFu + ((u >> 16) & 1u);
    return (unsigned short)(r >> 16);
}
__device__ __forceinline__ float bf2f(unsigned short s) {
    return __uint_as_float(((unsigned int)s) << 16);
}

// W_up f32 [640][256] -> bf16 [640][256]
__global__ void convert_w_kernel(const float* __restrict__ W, unsigned short* __restrict__ Wb) {
    int i = blockIdx.x * 256 + threadIdx.x;  // 40960 threads x 4 elems
    float4 v = ((const float4*)W)[i];
    unsigned short o[4] = {f2bf(v.x), f2bf(v.y), f2bf(v.z), f2bf(v.w)};
    *(ushort4*)(Wb + i * 4) = *(ushort4*)o;
}

// One tree-LSTM level via MFMA. X = x_in viewed as [n_par][256]
// (bf16 rows, or f32 leaf rows when FIRST). Out: h bf16, c f32, [n_par][128].
// Block: 256 thr = 4 waves; 32 parents/block; wave w owns output dims [32w,32w+32)
// for ALL 5 gates (n-subtiles g*128 + w*32 + nn*16) -> epilogue is wave-local.
template<bool FIRST>
__global__ __launch_bounds__(256)
void level_mfma_kernel(const void* __restrict__ x_in,
                       const float* __restrict__ c_in,
                       const unsigned short* __restrict__ Wb,
                       const float* __restrict__ b,
                       unsigned short* __restrict__ h_out,
                       float* __restrict__ c_out,
                       int n_par) {
    const int lane = threadIdx.x & 63;
    const int w = threadIdx.x >> 6;
    const int m0 = blockIdx.x * 32;
    const int col = lane & 15;
    const int kg = lane >> 4;  // k-chunk 0..3

    f32x4 acc[2][5][2];
    #pragma unroll
    for (int m = 0; m < 2; ++m)
        #pragma unroll
        for (int g = 0; g < 5; ++g)
            #pragma unroll
            for (int nn = 0; nn < 2; ++nn)
                acc[m][g][nn] = (f32x4){0.f, 0.f, 0.f, 0.f};

    // B-fragment base: row n = (w*32 + col) + g*128 + nn*16, k = kc*32 + kg*8
    const unsigned short* wrow = Wb + (size_t)(w * 32 + col) * 256 + kg * 8;

    const size_t rowA0 = (size_t)(m0 + col);
    const size_t rowA1 = (size_t)(m0 + 16 + col);

    #pragma unroll
    for (int kc = 0; kc < 8; ++kc) {
        short8 a0, a1;
        if (FIRST) {
            const float* x0 = (const float*)x_in + rowA0 * 256 + kg * 8 + kc * 32;
            const float* x1 = (const float*)x_in + rowA1 * 256 + kg * 8 + kc * 32;
            float4 u0 = *(const float4*)x0, u1 = *(const float4*)(x0 + 4);
            float4 v0 = *(const float4*)x1, v1 = *(const float4*)(x1 + 4);
            unsigned short t0[8] = {f2bf(u0.x), f2bf(u0.y), f2bf(u0.z), f2bf(u0.w),
                                    f2bf(u1.x), f2bf(u1.y), f2bf(u1.z), f2bf(u1.w)};
            unsigned short t1[8] = {f2bf(v0.x), f2bf(v0.y), f2bf(v0.z), f2bf(v0.w),
                                    f2bf(v1.x), f2bf(v1.y), f2bf(v1.z), f2bf(v1.w)};
            a0 = *(short8*)t0;
            a1 = *(short8*)t1;
        } else {
            const unsigned short* xb = (const unsigned short*)x_in;
            a0 = *(const short8*)(xb + rowA0 * 256 + kg * 8 + kc * 32);
            a1 = *(const short8*)(xb + rowA1 * 256 + kg * 8 + kc * 32);
        }
        #pragma unroll
        for (int g = 0; g < 5; ++g) {
            #pragma unroll
            for (int nn = 0; nn < 2; ++nn) {
                short8 bf = *(const short8*)(wrow + g * 32768 + nn * 4096 + kc * 32);
                acc[0][g][nn] = __builtin_amdgcn_mfma_f32_16x16x32_bf16(a0, bf, acc[0][g][nn], 0, 0, 0);
                acc[1][g][nn] = __builtin_amdgcn_mfma_f32_16x16x32_bf16(a1, bf, acc[1][g][nn], 0, 0, 0);
            }
        }
    }

    // bias: b[g*128 + w*32 + nn*16 + col]
    float bias[5][2];
    #pragma unroll
    for (int g = 0; g < 5; ++g)
        #pragma unroll
        for (int nn = 0; nn < 2; ++nn)
            bias[g][nn] = b[g * 128 + w * 32 + nn * 16 + col];

    #pragma unroll
    for (int m = 0; m < 2; ++m) {
        #pragma unroll
        for (int r = 0; r < 4; ++r) {
            const int P = m0 + m * 16 + kg * 4 + r;
            if (P < n_par) {
                #pragma unroll
                for (int nn = 0; nn < 2; ++nn) {
                    const int d = w * 32 + nn * 16 + col;
                    float iv = sigmoidf_(acc[m][0][nn][r] + bias[0][nn]);
                    float fl = sigmoidf_(acc[m][1][nn][r] + bias[1][nn]);
                    float fr = sigmoidf_(acc[m][2][nn][r] + bias[2][nn]);
                    float ov = sigmoidf_(acc[m][3][nn][r] + bias[3][nn]);
                    float gv = tanhf_(acc[m][4][nn][r] + bias[4][nn]);
                    float cl = 0.f, cr = 0.f;
                    if (!FIRST) {
                        cl = c_in[(size_t)(2 * P) * 128 + d];
                        cr = c_in[(size_t)(2 * P + 1) * 128 + d];
                    }
                    float cn = fl * cl + fr * cr + iv * gv;
                    float hn = ov * tanhf_(cn);
                    c_out[(size_t)P * 128 + d] = cn;
                    h_out[(size_t)P * 128 + d] = f2bf(hn);
                }
            }
        }
    }
}

// out[0:128] = mean of 4 bf16 roots; out[128:256] = 0
__global__ void root_kernel(const unsigned short* __restrict__ hf, float* __restrict__ out) {
    int t = threadIdx.x;
    if (t < 128) {
        out[t] = 0.25f * (bf2f(hf[t]) + bf2f(hf[128 + t]) + bf2f(hf[256 + t]) + bf2f(hf[384 + t]));
    } else if (t < 256) {
        out[t] = 0.0f;
    }
}

// leaves output row r -> [leaf_emb[r] (128 f32) | zeros (128)]
__global__ void copy_leaves_kernel(const float* __restrict__ leaf, float* __restrict__ out) {
    const float4* lf4 = (const float4*)leaf;
    float4* of4 = (float4*)(out + 256);
    const size_t total = (size_t)NRES * 64;
    for (size_t v = (size_t)blockIdx.x * blockDim.x + threadIdx.x; v < total;
         v += (size_t)gridDim.x * blockDim.x) {
        size_t r = v >> 6;
        int c = (int)(v & 63);
        float4 val = (c < 32) ? lf4[(r << 5) + c] : make_float4(0.f, 0.f, 0.f, 0.f);
        of4[v] = val;
    }
}

extern "C" void kernel_launch(void* const* d_in, const int* in_sizes, int n_in,
                              void* d_out, int out_size, void* d_ws, size_t ws_size,
                              hipStream_t stream) {
    const float* leaf = (const float*)d_in[0];
    const float* W_up = (const float*)d_in[1];
    const float* b_up = (const float*)d_in[2];
    float* out = (float*)d_out;
    char* base = (char*)d_out;

    // Carves from d_out (268 MB; everything overwritten by root+copy at the end):
    float* cA = (float*)(base);                             // 131072x128 f32 = 64 MiB
    float* cB = (float*)(base + 67108864);                  //  65536x128 f32 = 32 MiB
    unsigned short* hA = (unsigned short*)(base + 100663296); // 131072x128 bf16 = 32 MiB
    unsigned short* hB = (unsigned short*)(base + 134217728); //  65536x128 bf16 = 16 MiB
    unsigned short* Wb = (unsigned short*)(base + 150994944); // 640x256 bf16 = 320 KiB

    convert_w_kernel<<<160, 256, 0, stream>>>(W_up, Wb);

    int n_par = NRES / 2;  // 131072
    level_mfma_kernel<true><<<(n_par + 31) / 32, 256, 0, stream>>>(
        leaf, nullptr, Wb, b_up, hA, cA, n_par);

    const unsigned short* hin = hA;
    const float* cin = cA;
    unsigned short* ho = hB;
    float* co = cB;
    for (int lvl = 2; lvl <= 16; ++lvl) {
        n_par >>= 1;
        level_mfma_kernel<false><<<(n_par + 31) / 32, 256, 0, stream>>>(
            hin, cin, Wb, b_up, ho, co, n_par);
        const unsigned short* th = hin;
        const float* tc = cin;
        hin = ho; cin = co;
        ho = (unsigned short*)th; co = (float*)tc;
    }
    // 16 levels -> even -> final roots (4x128 bf16) are in hB
    root_kernel<<<1, 256, 0, stream>>>(hin, out);
    copy_leaves_kernel<<<4096, 256, 0, stream>>>(leaf, out);
}